// Round 2
// baseline (2391.266 us; speedup 1.0000x reference)
//
#include <hip/hip_runtime.h>
#include <hip/hip_bf16.h>

// ---------------------------------------------------------------------------
// GraphActorNetwork: movement MLP (16->128->128->128) -> scatter-mean over
// edges -> phase MLP (128->128->128->1).
// Round 2 = round 1 resubmitted (round-1 bench died on infra:
// UnresponsiveContainer before any kernel ran).
// f32 compute baseline. h stored bf16 in ws (accuracy cost ~1e-3,
// halves gather traffic + ws). Direct f32 atomic scatter (CSR in a later
// round if atomics dominate).
// ---------------------------------------------------------------------------

__device__ __forceinline__ float bf2f(unsigned short u) {
  return __uint_as_float(((unsigned int)u) << 16);
}
__device__ __forceinline__ unsigned short f2bf(float f) {
  unsigned int u = __float_as_uint(f);
  u = (u + 0x7fffu + ((u >> 16) & 1u)) >> 16;   // RNE
  return (unsigned short)u;
}

__device__ __forceinline__ void ld4(float* d, const float* s) {
  float4 v = *(const float4*)s;
  d[0] = v.x; d[1] = v.y; d[2] = v.z; d[3] = v.w;
}
__device__ __forceinline__ void st4(float* d, const float* s) {
  float4 v; v.x = s[0]; v.y = s[1]; v.z = s[2]; v.w = s[3];
  *(float4*)d = v;
}

// Swizzled LDS layout for transposed activations actT[c][r], 128x128 f32.
// Granule = 4 consecutive rows (16B). Swizzle spreads the transpose-writes
// (fixed r-granule, varying c) across bank groups while keeping the k-loop
// reads (fixed c=k, r-granules varying with tr) conflict-free (XOR with a
// per-instruction constant is bijective).
__device__ __forceinline__ int swz(int c) {
  return (c & 7) | (((c >> 3) & 1) << 4);
}
__device__ __forceinline__ int act_off(int c, int g) {   // g = r>>2; float index
  return (c << 7) + ((g ^ swz(c)) << 2);
}

// 64 accumulators: jj indexes channels {tc*4 + (jj>>2)*64 + (jj&3)}, rr rows.
__device__ __forceinline__ void layer128(float acc[8][8], const float* __restrict__ W,
                                         const float* sAct, int tc, int tr) {
#pragma unroll
  for (int jj = 0; jj < 8; ++jj)
#pragma unroll
    for (int rr = 0; rr < 8; ++rr) acc[jj][rr] = 0.f;
#pragma unroll 2
  for (int k = 0; k < 128; ++k) {
    float av[8], wv[8];
    ld4(av,     &sAct[act_off(k, 2 * tr)]);
    ld4(av + 4, &sAct[act_off(k, 2 * tr + 1)]);
    ld4(wv,     W + k * 128 + tc * 4);
    ld4(wv + 4, W + k * 128 + tc * 4 + 64);
#pragma unroll
    for (int jj = 0; jj < 8; ++jj)
#pragma unroll
      for (int rr = 0; rr < 8; ++rr)
        acc[jj][rr] = fmaf(wv[jj], av[rr], acc[jj][rr]);
  }
}

__device__ __forceinline__ void store_act(const float acc[8][8], const float* __restrict__ B,
                                          float* sAct, int tc, int tr) {
#pragma unroll
  for (int jj = 0; jj < 8; ++jj) {
    int c = tc * 4 + ((jj >> 2) << 6) + (jj & 3);
    float bb = B[c];
    float v[8];
#pragma unroll
    for (int rr = 0; rr < 8; ++rr) v[rr] = fmaxf(acc[jj][rr] + bb, 0.f);
    st4(&sAct[act_off(c, 2 * tr)],     v);
    st4(&sAct[act_off(c, 2 * tr + 1)], v + 4);
  }
}

// ---------------- movement MLP: x[nrows,16] -> h bf16[nrows,128] ------------
__global__ __launch_bounds__(256)
void mov_mlp_kernel(const float* __restrict__ x,
                    const float* __restrict__ W1, const float* __restrict__ b1,
                    const float* __restrict__ W2, const float* __restrict__ b2,
                    const float* __restrict__ W3, const float* __restrict__ b3,
                    unsigned short* __restrict__ hout, int nrows) {
  __shared__ float sAct[128 * 128];
  const int tid = threadIdx.x;
  const int tc = tid & 15, tr = tid >> 4;
  const int row0 = blockIdx.x << 7;
  const int rbase = row0 + tr * 8;

  float acc[8][8];

  // layer 1 (K=16), x read directly from global (L1-resident 8KB chunk)
#pragma unroll
  for (int jj = 0; jj < 8; ++jj)
#pragma unroll
    for (int rr = 0; rr < 8; ++rr) acc[jj][rr] = 0.f;
  {
    bool ok[8];
#pragma unroll
    for (int rr = 0; rr < 8; ++rr) ok[rr] = (rbase + rr) < nrows;
    for (int k = 0; k < 16; ++k) {
      float av[8], wv[8];
#pragma unroll
      for (int rr = 0; rr < 8; ++rr)
        av[rr] = ok[rr] ? x[(size_t)(rbase + rr) * 16 + k] : 0.f;
      ld4(wv,     W1 + k * 128 + tc * 4);
      ld4(wv + 4, W1 + k * 128 + tc * 4 + 64);
#pragma unroll
      for (int jj = 0; jj < 8; ++jj)
#pragma unroll
        for (int rr = 0; rr < 8; ++rr)
          acc[jj][rr] = fmaf(wv[jj], av[rr], acc[jj][rr]);
    }
  }
  store_act(acc, b1, sAct, tc, tr);
  __syncthreads();

  // layer 2
  layer128(acc, W2, sAct, tc, tr);
  __syncthreads();
  store_act(acc, b2, sAct, tc, tr);
  __syncthreads();

  // layer 3 -> bf16 global store from registers
  layer128(acc, W3, sAct, tc, tr);
  {
    float bb[8];
#pragma unroll
    for (int jj = 0; jj < 8; ++jj) bb[jj] = b3[tc * 4 + ((jj >> 2) << 6) + (jj & 3)];
#pragma unroll
    for (int rr = 0; rr < 8; ++rr) {
      int row = rbase + rr;
      if (row < nrows) {
#pragma unroll
        for (int jh = 0; jh < 2; ++jh) {
          ushort4 u;
          u.x = f2bf(fmaxf(acc[jh * 4 + 0][rr] + bb[jh * 4 + 0], 0.f));
          u.y = f2bf(fmaxf(acc[jh * 4 + 1][rr] + bb[jh * 4 + 1], 0.f));
          u.z = f2bf(fmaxf(acc[jh * 4 + 2][rr] + bb[jh * 4 + 2], 0.f));
          u.w = f2bf(fmaxf(acc[jh * 4 + 3][rr] + bb[jh * 4 + 3], 0.f));
          *(ushort4*)(hout + (size_t)row * 128 + tc * 4 + jh * 64) = u;
        }
      }
    }
  }
}

// ---------------- edge scatter: ssum += h[src], cnt += 1 --------------------
__global__ __launch_bounds__(256)
void scatter_kernel(const unsigned short* __restrict__ h,
                    const int* __restrict__ esrc, const int* __restrict__ edst,
                    float* __restrict__ ssum, float* __restrict__ cnt, int ne) {
  const int t = blockIdx.x * blockDim.x + threadIdx.x;
  const int g = t & 31;
  const int estep = (gridDim.x * blockDim.x) >> 5;
  for (int e = t >> 5; e < ne; e += estep) {
    int s = esrc[e], d = edst[e];
    ushort4 v = *(const ushort4*)(h + (size_t)s * 128 + g * 4);
    float* o = ssum + (size_t)d * 128 + g * 4;
    atomicAdd(o + 0, bf2f(v.x));
    atomicAdd(o + 1, bf2f(v.y));
    atomicAdd(o + 2, bf2f(v.z));
    atomicAdd(o + 3, bf2f(v.w));
    if (g == 0) atomicAdd(cnt + d, 1.0f);
  }
}

// ---------------- phase MLP: agg -> relu -> relu -> scalar ------------------
__global__ __launch_bounds__(256)
void phase_mlp_kernel(const float* __restrict__ ssum, const float* __restrict__ cnt,
                      const float* __restrict__ W4, const float* __restrict__ b4,
                      const float* __restrict__ W5, const float* __restrict__ b5,
                      const float* __restrict__ W6, const float* __restrict__ b6,
                      float* __restrict__ logits, int nph) {
  __shared__ float sAct[128 * 128];
  const int tid = threadIdx.x;
  const int tc = tid & 15, tr = tid >> 4;
  const int row0 = blockIdx.x << 7;

  // stage agg = ssum / max(cnt,1), transposed + swizzled
  for (int i = tid; i < 128 * 128; i += 256) {
    int r = i >> 7, c = i & 127;
    int gr = row0 + r;
    float v = 0.f;
    if (gr < nph) {
      float cc = cnt[gr];
      v = ssum[(size_t)gr * 128 + c] / fmaxf(cc, 1.f);
    }
    sAct[act_off(c, r >> 2) + (r & 3)] = v;
  }
  __syncthreads();

  float acc[8][8];
  layer128(acc, W4, sAct, tc, tr);
  __syncthreads();
  store_act(acc, b4, sAct, tc, tr);
  __syncthreads();
  layer128(acc, W5, sAct, tc, tr);
  __syncthreads();
  store_act(acc, b5, sAct, tc, tr);
  __syncthreads();

  // head: logits[r] = p[r,:] . W6 + b6
  if (tid < 128) {
    int r = tid;
    float a = b6[0];
    for (int c = 0; c < 128; ++c)
      a += sAct[act_off(c, r >> 2) + (r & 3)] * W6[c];
    int gr = row0 + r;
    if (gr < nph) logits[gr] = a;
  }
}

// ---------------------------------------------------------------------------
extern "C" void kernel_launch(void* const* d_in, const int* in_sizes, int n_in,
                              void* d_out, int out_size, void* d_ws, size_t ws_size,
                              hipStream_t stream) {
  const float* x  = (const float*)d_in[0];
  const float* W1 = (const float*)d_in[1];
  const float* b1 = (const float*)d_in[2];
  const float* W2 = (const float*)d_in[3];
  const float* b2 = (const float*)d_in[4];
  const float* W3 = (const float*)d_in[5];
  const float* b3 = (const float*)d_in[6];
  const float* W4 = (const float*)d_in[7];
  const float* b4 = (const float*)d_in[8];
  const float* W5 = (const float*)d_in[9];
  const float* b5 = (const float*)d_in[10];
  const float* W6 = (const float*)d_in[11];
  const float* b6 = (const float*)d_in[12];
  const int* esrc = (const int*)d_in[13];
  const int* edst = (const int*)d_in[14];

  const int nmov = in_sizes[0] / 16;
  const int ne   = in_sizes[13];
  const int nph  = out_size;

  char* ws = (char*)d_ws;
  unsigned short* hbuf = (unsigned short*)ws;              // nmov*128 bf16
  size_t off_s = (size_t)nmov * 128 * sizeof(unsigned short);
  float* ssum = (float*)(ws + off_s);                      // nph*128 f32
  float* cnt  = (float*)(ws + off_s + (size_t)nph * 128 * sizeof(float));

  size_t need = off_s + (size_t)nph * 129 * sizeof(float);
  if (ws_size < need) return;  // cannot run without scratch

  // zero ssum + cnt (contiguous)
  hipMemsetAsync(ssum, 0, (size_t)nph * 129 * sizeof(float), stream);

  int movBlocks = (nmov + 127) / 128;
  mov_mlp_kernel<<<movBlocks, 256, 0, stream>>>(x, W1, b1, W2, b2, W3, b3, hbuf, nmov);

  scatter_kernel<<<2048, 256, 0, stream>>>(hbuf, esrc, edst, ssum, cnt, ne);

  int phBlocks = (nph + 127) / 128;
  phase_mlp_kernel<<<phBlocks, 256, 0, stream>>>(ssum, cnt, W4, b4, W5, b5, W6, b6,
                                                 (float*)d_out, nph);
}

// Round 4
// 1092.396 us; speedup vs baseline: 2.1890x; 2.1890x over previous
//
#include <hip/hip_runtime.h>
#include <hip/hip_bf16.h>

// ---------------------------------------------------------------------------
// GraphActorNetwork: movement MLP (16->128->128->128) -> scatter-mean over
// edges -> phase MLP (128->128->128->1).
// Round 4 = round 3 resubmitted (round-3 bench died on infra:
// UnresponsiveContainer before any kernel ran).
// Replace f32 atomic scatter (1723us, atomic-RMW bound, 2GB write
// amplification) with CSR build (hist + scan + fill, int atomics only) +
// per-phase wave gather-reduce from L3-resident bf16 h. agg stored bf16.
// mov_mlp/phase_mlp unchanged f32 (MFMA candidate next round).
// ---------------------------------------------------------------------------

__device__ __forceinline__ float bf2f(unsigned short u) {
  return __uint_as_float(((unsigned int)u) << 16);
}
__device__ __forceinline__ unsigned short f2bf(float f) {
  unsigned int u = __float_as_uint(f);
  u = (u + 0x7fffu + ((u >> 16) & 1u)) >> 16;   // RNE
  return (unsigned short)u;
}

__device__ __forceinline__ void ld4(float* d, const float* s) {
  float4 v = *(const float4*)s;
  d[0] = v.x; d[1] = v.y; d[2] = v.z; d[3] = v.w;
}
__device__ __forceinline__ void st4(float* d, const float* s) {
  float4 v; v.x = s[0]; v.y = s[1]; v.z = s[2]; v.w = s[3];
  *(float4*)d = v;
}

// Swizzled LDS layout for transposed activations actT[c][r], 128x128 f32.
__device__ __forceinline__ int swz(int c) {
  return (c & 7) | (((c >> 3) & 1) << 4);
}
__device__ __forceinline__ int act_off(int c, int g) {   // g = r>>2; float index
  return (c << 7) + ((g ^ swz(c)) << 2);
}

// 64 accumulators: jj indexes channels {tc*4 + (jj>>2)*64 + (jj&3)}, rr rows.
__device__ __forceinline__ void layer128(float acc[8][8], const float* __restrict__ W,
                                         const float* sAct, int tc, int tr) {
#pragma unroll
  for (int jj = 0; jj < 8; ++jj)
#pragma unroll
    for (int rr = 0; rr < 8; ++rr) acc[jj][rr] = 0.f;
#pragma unroll 2
  for (int k = 0; k < 128; ++k) {
    float av[8], wv[8];
    ld4(av,     &sAct[act_off(k, 2 * tr)]);
    ld4(av + 4, &sAct[act_off(k, 2 * tr + 1)]);
    ld4(wv,     W + k * 128 + tc * 4);
    ld4(wv + 4, W + k * 128 + tc * 4 + 64);
#pragma unroll
    for (int jj = 0; jj < 8; ++jj)
#pragma unroll
      for (int rr = 0; rr < 8; ++rr)
        acc[jj][rr] = fmaf(wv[jj], av[rr], acc[jj][rr]);
  }
}

__device__ __forceinline__ void store_act(const float acc[8][8], const float* __restrict__ B,
                                          float* sAct, int tc, int tr) {
#pragma unroll
  for (int jj = 0; jj < 8; ++jj) {
    int c = tc * 4 + ((jj >> 2) << 6) + (jj & 3);
    float bb = B[c];
    float v[8];
#pragma unroll
    for (int rr = 0; rr < 8; ++rr) v[rr] = fmaxf(acc[jj][rr] + bb, 0.f);
    st4(&sAct[act_off(c, 2 * tr)],     v);
    st4(&sAct[act_off(c, 2 * tr + 1)], v + 4);
  }
}

// ---------------- movement MLP: x[nrows,16] -> h bf16[nrows,128] ------------
__global__ __launch_bounds__(256)
void mov_mlp_kernel(const float* __restrict__ x,
                    const float* __restrict__ W1, const float* __restrict__ b1,
                    const float* __restrict__ W2, const float* __restrict__ b2,
                    const float* __restrict__ W3, const float* __restrict__ b3,
                    unsigned short* __restrict__ hout, int nrows) {
  __shared__ float sAct[128 * 128];
  const int tid = threadIdx.x;
  const int tc = tid & 15, tr = tid >> 4;
  const int row0 = blockIdx.x << 7;
  const int rbase = row0 + tr * 8;

  float acc[8][8];

#pragma unroll
  for (int jj = 0; jj < 8; ++jj)
#pragma unroll
    for (int rr = 0; rr < 8; ++rr) acc[jj][rr] = 0.f;
  {
    bool ok[8];
#pragma unroll
    for (int rr = 0; rr < 8; ++rr) ok[rr] = (rbase + rr) < nrows;
    for (int k = 0; k < 16; ++k) {
      float av[8], wv[8];
#pragma unroll
      for (int rr = 0; rr < 8; ++rr)
        av[rr] = ok[rr] ? x[(size_t)(rbase + rr) * 16 + k] : 0.f;
      ld4(wv,     W1 + k * 128 + tc * 4);
      ld4(wv + 4, W1 + k * 128 + tc * 4 + 64);
#pragma unroll
      for (int jj = 0; jj < 8; ++jj)
#pragma unroll
        for (int rr = 0; rr < 8; ++rr)
          acc[jj][rr] = fmaf(wv[jj], av[rr], acc[jj][rr]);
    }
  }
  store_act(acc, b1, sAct, tc, tr);
  __syncthreads();

  layer128(acc, W2, sAct, tc, tr);
  __syncthreads();
  store_act(acc, b2, sAct, tc, tr);
  __syncthreads();

  layer128(acc, W3, sAct, tc, tr);
  {
    float bb[8];
#pragma unroll
    for (int jj = 0; jj < 8; ++jj) bb[jj] = b3[tc * 4 + ((jj >> 2) << 6) + (jj & 3)];
#pragma unroll
    for (int rr = 0; rr < 8; ++rr) {
      int row = rbase + rr;
      if (row < nrows) {
#pragma unroll
        for (int jh = 0; jh < 2; ++jh) {
          ushort4 u;
          u.x = f2bf(fmaxf(acc[jh * 4 + 0][rr] + bb[jh * 4 + 0], 0.f));
          u.y = f2bf(fmaxf(acc[jh * 4 + 1][rr] + bb[jh * 4 + 1], 0.f));
          u.z = f2bf(fmaxf(acc[jh * 4 + 2][rr] + bb[jh * 4 + 2], 0.f));
          u.w = f2bf(fmaxf(acc[jh * 4 + 3][rr] + bb[jh * 4 + 3], 0.f));
          *(ushort4*)(hout + (size_t)row * 128 + tc * 4 + jh * 64) = u;
        }
      }
    }
  }
}

// ---------------- CSR build ------------------------------------------------
__global__ __launch_bounds__(256)
void hist_kernel(const int* __restrict__ edst, int* __restrict__ cnt, int ne) {
  int i = blockIdx.x * blockDim.x + threadIdx.x;
  int stride = gridDim.x * blockDim.x;
  for (int e = i; e < ne; e += stride) atomicAdd(cnt + edst[e], 1);
}

// single-block exclusive scan: cnt[nph] -> offs[nph+1], cursor[nph]
__global__ __launch_bounds__(1024)
void scan_kernel(const int* __restrict__ cnt, int* __restrict__ offs,
                 int* __restrict__ cursor, int nph) {
  __shared__ int part[1024];
  const int tid = threadIdx.x;
  const int per = (nph + 1023) >> 10;
  const int beg = tid * per;
  const int end = min(beg + per, nph);
  int s = 0;
  for (int i = beg; i < end; ++i) s += cnt[i];
  part[tid] = s;
  __syncthreads();
  // Hillis-Steele inclusive scan
  for (int d = 1; d < 1024; d <<= 1) {
    int v = (tid >= d) ? part[tid - d] : 0;
    __syncthreads();
    part[tid] += v;
    __syncthreads();
  }
  if (tid == 0) offs[nph] = part[1023];
  int run = (tid == 0) ? 0 : part[tid - 1];
  for (int i = beg; i < end; ++i) {
    offs[i] = run;
    cursor[i] = run;
    run += cnt[i];
  }
}

__global__ __launch_bounds__(256)
void fill_kernel(const int* __restrict__ esrc, const int* __restrict__ edst,
                 int* __restrict__ cursor, int* __restrict__ csr, int ne) {
  int i = blockIdx.x * blockDim.x + threadIdx.x;
  int stride = gridDim.x * blockDim.x;
  for (int e = i; e < ne; e += stride) {
    int d = edst[e];
    int pos = atomicAdd(cursor + d, 1);
    csr[pos] = esrc[e];
  }
}

// ---------------- per-phase gather-reduce: one wave per phase ---------------
__global__ __launch_bounds__(256)
void agg_kernel(const unsigned short* __restrict__ h, const int* __restrict__ csr,
                const int* __restrict__ offs, unsigned short* __restrict__ agg,
                int nph) {
  const int w = (blockIdx.x * blockDim.x + threadIdx.x) >> 6;
  const int lane = threadIdx.x & 63;
  if (w >= nph) return;
  const int beg = offs[w], end = offs[w + 1];
  float a0 = 0.f, a1 = 0.f;
  for (int j = beg; j < end; ++j) {
    int s = csr[j];
    ushort2 v = *(const ushort2*)(h + (size_t)s * 128 + lane * 2);
    a0 += bf2f(v.x);
    a1 += bf2f(v.y);
  }
  const float sc = 1.f / (float)max(end - beg, 1);
  ushort2 o;
  o.x = f2bf(a0 * sc);
  o.y = f2bf(a1 * sc);
  *(ushort2*)(agg + (size_t)w * 128 + lane * 2) = o;
}

// ---------------- phase MLP: agg(bf16) -> relu -> relu -> scalar ------------
__global__ __launch_bounds__(256)
void phase_mlp_kernel(const unsigned short* __restrict__ agg,
                      const float* __restrict__ W4, const float* __restrict__ b4,
                      const float* __restrict__ W5, const float* __restrict__ b5,
                      const float* __restrict__ W6, const float* __restrict__ b6,
                      float* __restrict__ logits, int nph) {
  __shared__ float sAct[128 * 128];
  const int tid = threadIdx.x;
  const int tc = tid & 15, tr = tid >> 4;
  const int row0 = blockIdx.x << 7;

  // stage agg transposed + swizzled
  for (int i = tid; i < 128 * 128; i += 256) {
    int r = i >> 7, c = i & 127;
    int gr = row0 + r;
    float v = 0.f;
    if (gr < nph) v = bf2f(agg[(size_t)gr * 128 + c]);
    sAct[act_off(c, r >> 2) + (r & 3)] = v;
  }
  __syncthreads();

  float acc[8][8];
  layer128(acc, W4, sAct, tc, tr);
  __syncthreads();
  store_act(acc, b4, sAct, tc, tr);
  __syncthreads();
  layer128(acc, W5, sAct, tc, tr);
  __syncthreads();
  store_act(acc, b5, sAct, tc, tr);
  __syncthreads();

  if (tid < 128) {
    int r = tid;
    float a = b6[0];
    for (int c = 0; c < 128; ++c)
      a += sAct[act_off(c, r >> 2) + (r & 3)] * W6[c];
    int gr = row0 + r;
    if (gr < nph) logits[gr] = a;
  }
}

// ---------------------------------------------------------------------------
extern "C" void kernel_launch(void* const* d_in, const int* in_sizes, int n_in,
                              void* d_out, int out_size, void* d_ws, size_t ws_size,
                              hipStream_t stream) {
  const float* x  = (const float*)d_in[0];
  const float* W1 = (const float*)d_in[1];
  const float* b1 = (const float*)d_in[2];
  const float* W2 = (const float*)d_in[3];
  const float* b2 = (const float*)d_in[4];
  const float* W3 = (const float*)d_in[5];
  const float* b3 = (const float*)d_in[6];
  const float* W4 = (const float*)d_in[7];
  const float* b4 = (const float*)d_in[8];
  const float* W5 = (const float*)d_in[9];
  const float* b5 = (const float*)d_in[10];
  const float* W6 = (const float*)d_in[11];
  const float* b6 = (const float*)d_in[12];
  const int* esrc = (const int*)d_in[13];
  const int* edst = (const int*)d_in[14];

  const int nmov = in_sizes[0] / 16;
  const int ne   = in_sizes[13];
  const int nph  = out_size;

  char* ws = (char*)d_ws;
  size_t off = 0;
  auto take = [&](size_t bytes) {
    char* p = ws + off;
    off = (off + bytes + 255) & ~(size_t)255;
    return p;
  };
  unsigned short* hbuf = (unsigned short*)take((size_t)nmov * 128 * 2); // 128 MB
  int* csr             = (int*)take((size_t)ne * 4);                   //   4 MB
  int* cnt             = (int*)take((size_t)nph * 4);                  // 0.5 MB
  int* offs            = (int*)take(((size_t)nph + 1) * 4);            // 0.5 MB
  int* cursor          = (int*)take((size_t)nph * 4);                  // 0.5 MB
  unsigned short* aggb = (unsigned short*)take((size_t)nph * 128 * 2); //  32 MB
  if (off > ws_size) return;  // ~165.5 MB needed

  hipMemsetAsync(cnt, 0, (size_t)nph * 4, stream);

  int movBlocks = (nmov + 127) / 128;
  mov_mlp_kernel<<<movBlocks, 256, 0, stream>>>(x, W1, b1, W2, b2, W3, b3, hbuf, nmov);

  hist_kernel<<<1024, 256, 0, stream>>>(edst, cnt, ne);
  scan_kernel<<<1, 1024, 0, stream>>>(cnt, offs, cursor, nph);
  fill_kernel<<<1024, 256, 0, stream>>>(esrc, edst, cursor, csr, ne);

  int aggBlocks = (nph + 3) / 4;  // 4 waves (phases) per 256-thread block
  agg_kernel<<<aggBlocks, 256, 0, stream>>>(hbuf, csr, offs, aggb, nph);

  int phBlocks = (nph + 127) / 128;
  phase_mlp_kernel<<<phBlocks, 256, 0, stream>>>(aggb, W4, b4, W5, b5, W6, b6,
                                                 (float*)d_out, nph);
}

// Round 6
// 825.289 us; speedup vs baseline: 2.8975x; 1.3237x over previous
//
#include <hip/hip_runtime.h>
#include <hip/hip_bf16.h>

// ---------------------------------------------------------------------------
// GraphActorNetwork: movement MLP (16->128->128->128) -> scatter-mean over
// edges -> phase MLP (128->128->128->1).
// Round 6 = round 5 resubmitted (round-5 bench died on infra:
// UnresponsiveContainer before any kernel ran).
// Movement MLP on bf16 MFMA (16x16x32), weights register-hoisted from
// pre-transposed bf16 copies in ws; activations in a 16KB XOR-swizzled LDS
// tile. CSR aggregation path unchanged from round 4 (2391 -> 1092 us).
// mov_mlp was 520 us f32-VALU-bound (VALUBusy 65%, MfmaUtil 0).
// ---------------------------------------------------------------------------

typedef __attribute__((ext_vector_type(8))) short short8;
typedef __attribute__((ext_vector_type(4))) float f32x4;

__device__ __forceinline__ float bf2f(unsigned short u) {
  return __uint_as_float(((unsigned int)u) << 16);
}
__device__ __forceinline__ unsigned short f2bf(float f) {
  unsigned int u = __float_as_uint(f);
  u = (u + 0x7fffu + ((u >> 16) & 1u)) >> 16;   // RNE
  return (unsigned short)u;
}

__device__ __forceinline__ void ld4(float* d, const float* s) {
  float4 v = *(const float4*)s;
  d[0] = v.x; d[1] = v.y; d[2] = v.z; d[3] = v.w;
}
__device__ __forceinline__ void st4(float* d, const float* s) {
  float4 v; v.x = s[0]; v.y = s[1]; v.z = s[2]; v.w = s[3];
  *(float4*)d = v;
}

// f32 phase-MLP swizzled LDS layout (unchanged from round 4)
__device__ __forceinline__ int swz(int c) {
  return (c & 7) | (((c >> 3) & 1) << 4);
}
__device__ __forceinline__ int act_off(int c, int g) {
  return (c << 7) + ((g ^ swz(c)) << 2);
}

__device__ __forceinline__ void layer128(float acc[8][8], const float* __restrict__ W,
                                         const float* sAct, int tc, int tr) {
#pragma unroll
  for (int jj = 0; jj < 8; ++jj)
#pragma unroll
    for (int rr = 0; rr < 8; ++rr) acc[jj][rr] = 0.f;
#pragma unroll 2
  for (int k = 0; k < 128; ++k) {
    float av[8], wv[8];
    ld4(av,     &sAct[act_off(k, 2 * tr)]);
    ld4(av + 4, &sAct[act_off(k, 2 * tr + 1)]);
    ld4(wv,     W + k * 128 + tc * 4);
    ld4(wv + 4, W + k * 128 + tc * 4 + 64);
#pragma unroll
    for (int jj = 0; jj < 8; ++jj)
#pragma unroll
      for (int rr = 0; rr < 8; ++rr)
        acc[jj][rr] = fmaf(wv[jj], av[rr], acc[jj][rr]);
  }
}

__device__ __forceinline__ void store_act(const float acc[8][8], const float* __restrict__ B,
                                          float* sAct, int tc, int tr) {
#pragma unroll
  for (int jj = 0; jj < 8; ++jj) {
    int c = tc * 4 + ((jj >> 2) << 6) + (jj & 3);
    float bb = B[c];
    float v[8];
#pragma unroll
    for (int rr = 0; rr < 8; ++rr) v[rr] = fmaxf(acc[jj][rr] + bb, 0.f);
    st4(&sAct[act_off(c, 2 * tr)],     v);
    st4(&sAct[act_off(c, 2 * tr + 1)], v + 4);
  }
}

// ---------------- weight prep: f32 -> bf16 transposed -----------------------
// w1t: [128 c][32 k] (k 16..31 zero);  w2t,w3t: [128 c][128 k]
__global__ __launch_bounds__(256)
void prep_weights(const float* __restrict__ W1, const float* __restrict__ W2,
                  const float* __restrict__ W3,
                  unsigned short* __restrict__ w1t, unsigned short* __restrict__ w2t,
                  unsigned short* __restrict__ w3t) {
  int t = blockIdx.x * blockDim.x + threadIdx.x;
  int stride = gridDim.x * blockDim.x;
  if (t < 128 * 32) {
    int c = t >> 5, k = t & 31;
    w1t[t] = (k < 16) ? f2bf(W1[k * 128 + c]) : 0;
  }
  for (int i = t; i < 128 * 128; i += stride) {
    int c = i >> 7, k = i & 127;
    w2t[i] = f2bf(W2[k * 128 + c]);
    w3t[i] = f2bf(W3[k * 128 + c]);
  }
}

// ---------------- movement MLP via MFMA -------------------------------------
// Block: 256 threads = 4 waves, tile 64 rows x 128 cols.
// Wave w: rows (w&1)*32..+31, cols (w>>1)*64..+63 (2 row-frags x 4 col-frags).
// sH: bf16 [64][128], 16B granules XOR-swizzled by (row&7).
__global__ __launch_bounds__(256)
void mov_mlp_mfma(const float* __restrict__ x,
                  const unsigned short* __restrict__ w1t,
                  const unsigned short* __restrict__ w2t,
                  const unsigned short* __restrict__ w3t,
                  const float* __restrict__ b1, const float* __restrict__ b2,
                  const float* __restrict__ b3,
                  unsigned short* __restrict__ hout, int nrows) {
  __shared__ unsigned short sH[64 * 128];
  const int tid  = threadIdx.x;
  const int lane = tid & 63;
  const int w    = tid >> 6;
  const int rloc = lane & 15;     // row (A/D col) index within fragment
  const int g    = lane >> 4;     // k-group
  const int r0w  = (w & 1) * 32;  // wave row base in tile
  const int c0   = (w >> 1) * 64; // wave col base
  const int rowBlk = blockIdx.x * 64;

  f32x4 acc[2][4];
  short8 Bf[4][4];   // [ks][cf] hoisted weights

  // ---- layer 1: A from global x (K=32, cols 16..31 zero) ----
#pragma unroll
  for (int rf = 0; rf < 2; ++rf)
#pragma unroll
    for (int cf = 0; cf < 4; ++cf) acc[rf][cf] = (f32x4)0.f;

  {
    short8 Ax[2];
#pragma unroll
    for (int rf = 0; rf < 2; ++rf) {
      short8 a = (short8)0;
      int row = rowBlk + r0w + rf * 16 + rloc;
      if (g < 2 && row < nrows) {
        const float* xp = x + (size_t)row * 16 + g * 8;
        float4 u0 = *(const float4*)xp;
        float4 u1 = *(const float4*)(xp + 4);
        a[0] = (short)f2bf(u0.x); a[1] = (short)f2bf(u0.y);
        a[2] = (short)f2bf(u0.z); a[3] = (short)f2bf(u0.w);
        a[4] = (short)f2bf(u1.x); a[5] = (short)f2bf(u1.y);
        a[6] = (short)f2bf(u1.z); a[7] = (short)f2bf(u1.w);
      }
      Ax[rf] = a;
    }
    short8 B1[4];
#pragma unroll
    for (int cf = 0; cf < 4; ++cf)
      B1[cf] = *(const short8*)&w1t[(c0 + cf * 16 + rloc) * 32 + g * 8];
#pragma unroll
    for (int rf = 0; rf < 2; ++rf)
#pragma unroll
      for (int cf = 0; cf < 4; ++cf)
        acc[rf][cf] = __builtin_amdgcn_mfma_f32_16x16x32_bf16(Ax[rf], B1[cf], acc[rf][cf], 0, 0, 0);
  }

  // epilogue layer1 -> sH
  {
    float bv[4];
#pragma unroll
    for (int cf = 0; cf < 4; ++cf) bv[cf] = b1[c0 + cf * 16 + rloc];
#pragma unroll
    for (int rf = 0; rf < 2; ++rf)
#pragma unroll
      for (int cf = 0; cf < 4; ++cf)
#pragma unroll
        for (int i = 0; i < 4; ++i) {
          int row = r0w + rf * 16 + g * 4 + i;
          int col = c0 + cf * 16 + rloc;
          float v = fmaxf(acc[rf][cf][i] + bv[cf], 0.f);
          sH[row * 128 + (((col >> 3) ^ (row & 7)) << 3) + (col & 7)] = f2bf(v);
        }
  }
  __syncthreads();

  // ---- layers 2 and 3: A from sH, B hoisted from wt ----
  const unsigned short* wts[2] = { w2t, w3t };
  const float* bs[2] = { b2, b3 };
#pragma unroll 1
  for (int layer = 0; layer < 2; ++layer) {
    const unsigned short* wt = wts[layer];
#pragma unroll
    for (int ks = 0; ks < 4; ++ks)
#pragma unroll
      for (int cf = 0; cf < 4; ++cf)
        Bf[ks][cf] = *(const short8*)&wt[(c0 + cf * 16 + rloc) * 128 + ks * 32 + g * 8];

#pragma unroll
    for (int rf = 0; rf < 2; ++rf)
#pragma unroll
      for (int cf = 0; cf < 4; ++cf) acc[rf][cf] = (f32x4)0.f;

#pragma unroll
    for (int ks = 0; ks < 4; ++ks) {
      short8 A0, A1;
      {
        int row = r0w + rloc;
        int slot = (ks * 4 + g) ^ (row & 7);
        A0 = *(const short8*)&sH[row * 128 + slot * 8];
      }
      {
        int row = r0w + 16 + rloc;
        int slot = (ks * 4 + g) ^ (row & 7);
        A1 = *(const short8*)&sH[row * 128 + slot * 8];
      }
#pragma unroll
      for (int cf = 0; cf < 4; ++cf) {
        acc[0][cf] = __builtin_amdgcn_mfma_f32_16x16x32_bf16(A0, Bf[ks][cf], acc[0][cf], 0, 0, 0);
        acc[1][cf] = __builtin_amdgcn_mfma_f32_16x16x32_bf16(A1, Bf[ks][cf], acc[1][cf], 0, 0, 0);
      }
    }
    __syncthreads();   // all reads of sH done before overwrite

    const float* bb = bs[layer];
    float bv[4];
#pragma unroll
    for (int cf = 0; cf < 4; ++cf) bv[cf] = bb[c0 + cf * 16 + rloc];
#pragma unroll
    for (int rf = 0; rf < 2; ++rf)
#pragma unroll
      for (int cf = 0; cf < 4; ++cf)
#pragma unroll
        for (int i = 0; i < 4; ++i) {
          int row = r0w + rf * 16 + g * 4 + i;
          int col = c0 + cf * 16 + rloc;
          float v = fmaxf(acc[rf][cf][i] + bv[cf], 0.f);
          sH[row * 128 + (((col >> 3) ^ (row & 7)) << 3) + (col & 7)] = f2bf(v);
        }
    __syncthreads();
  }

  // ---- coalesced copy-out: sH -> hout (16B/lane) ----
  {
    int row = tid >> 2;           // 0..63
    int q   = tid & 3;            // col quarter
    int grow = rowBlk + row;
    if (grow < nrows) {
#pragma unroll
      for (int i = 0; i < 4; ++i) {
        int gidx = q * 4 + i;                 // logical granule (8 cols)
        int slot = gidx ^ (row & 7);
        short8 v = *(const short8*)&sH[row * 128 + slot * 8];
        *(short8*)(hout + (size_t)grow * 128 + gidx * 8) = v;
      }
    }
  }
}

// ---------------- CSR build ------------------------------------------------
__global__ __launch_bounds__(256)
void hist_kernel(const int* __restrict__ edst, int* __restrict__ cnt, int ne) {
  int i = blockIdx.x * blockDim.x + threadIdx.x;
  int stride = gridDim.x * blockDim.x;
  for (int e = i; e < ne; e += stride) atomicAdd(cnt + edst[e], 1);
}

__global__ __launch_bounds__(1024)
void scan_kernel(const int* __restrict__ cnt, int* __restrict__ offs,
                 int* __restrict__ cursor, int nph) {
  __shared__ int part[1024];
  const int tid = threadIdx.x;
  const int per = (nph + 1023) >> 10;
  const int beg = tid * per;
  const int end = min(beg + per, nph);
  int s = 0;
  for (int i = beg; i < end; ++i) s += cnt[i];
  part[tid] = s;
  __syncthreads();
  for (int d = 1; d < 1024; d <<= 1) {
    int v = (tid >= d) ? part[tid - d] : 0;
    __syncthreads();
    part[tid] += v;
    __syncthreads();
  }
  if (tid == 0) offs[nph] = part[1023];
  int run = (tid == 0) ? 0 : part[tid - 1];
  for (int i = beg; i < end; ++i) {
    offs[i] = run;
    cursor[i] = run;
    run += cnt[i];
  }
}

__global__ __launch_bounds__(256)
void fill_kernel(const int* __restrict__ esrc, const int* __restrict__ edst,
                 int* __restrict__ cursor, int* __restrict__ csr, int ne) {
  int i = blockIdx.x * blockDim.x + threadIdx.x;
  int stride = gridDim.x * blockDim.x;
  for (int e = i; e < ne; e += stride) {
    int d = edst[e];
    int pos = atomicAdd(cursor + d, 1);
    csr[pos] = esrc[e];
  }
}

// ---------------- per-phase gather-reduce: one wave per phase ---------------
__global__ __launch_bounds__(256)
void agg_kernel(const unsigned short* __restrict__ h, const int* __restrict__ csr,
                const int* __restrict__ offs, unsigned short* __restrict__ agg,
                int nph) {
  const int w = (blockIdx.x * blockDim.x + threadIdx.x) >> 6;
  const int lane = threadIdx.x & 63;
  if (w >= nph) return;
  const int beg = offs[w], end = offs[w + 1];
  float a0 = 0.f, a1 = 0.f;
  for (int j = beg; j < end; ++j) {
    int s = csr[j];
    ushort2 v = *(const ushort2*)(h + (size_t)s * 128 + lane * 2);
    a0 += bf2f(v.x);
    a1 += bf2f(v.y);
  }
  const float sc = 1.f / (float)max(end - beg, 1);
  ushort2 o;
  o.x = f2bf(a0 * sc);
  o.y = f2bf(a1 * sc);
  *(ushort2*)(agg + (size_t)w * 128 + lane * 2) = o;
}

// ---------------- phase MLP (f32, unchanged) --------------------------------
__global__ __launch_bounds__(256)
void phase_mlp_kernel(const unsigned short* __restrict__ agg,
                      const float* __restrict__ W4, const float* __restrict__ b4,
                      const float* __restrict__ W5, const float* __restrict__ b5,
                      const float* __restrict__ W6, const float* __restrict__ b6,
                      float* __restrict__ logits, int nph) {
  __shared__ float sAct[128 * 128];
  const int tid = threadIdx.x;
  const int tc = tid & 15, tr = tid >> 4;
  const int row0 = blockIdx.x << 7;

  for (int i = tid; i < 128 * 128; i += 256) {
    int r = i >> 7, c = i & 127;
    int gr = row0 + r;
    float v = 0.f;
    if (gr < nph) v = bf2f(agg[(size_t)gr * 128 + c]);
    sAct[act_off(c, r >> 2) + (r & 3)] = v;
  }
  __syncthreads();

  float acc[8][8];
  layer128(acc, W4, sAct, tc, tr);
  __syncthreads();
  store_act(acc, b4, sAct, tc, tr);
  __syncthreads();
  layer128(acc, W5, sAct, tc, tr);
  __syncthreads();
  store_act(acc, b5, sAct, tc, tr);
  __syncthreads();

  if (tid < 128) {
    int r = tid;
    float a = b6[0];
    for (int c = 0; c < 128; ++c)
      a += sAct[act_off(c, r >> 2) + (r & 3)] * W6[c];
    int gr = row0 + r;
    if (gr < nph) logits[gr] = a;
  }
}

// ---------------------------------------------------------------------------
extern "C" void kernel_launch(void* const* d_in, const int* in_sizes, int n_in,
                              void* d_out, int out_size, void* d_ws, size_t ws_size,
                              hipStream_t stream) {
  const float* x  = (const float*)d_in[0];
  const float* W1 = (const float*)d_in[1];
  const float* b1 = (const float*)d_in[2];
  const float* W2 = (const float*)d_in[3];
  const float* b2 = (const float*)d_in[4];
  const float* W3 = (const float*)d_in[5];
  const float* b3 = (const float*)d_in[6];
  const float* W4 = (const float*)d_in[7];
  const float* b4 = (const float*)d_in[8];
  const float* W5 = (const float*)d_in[9];
  const float* b5 = (const float*)d_in[10];
  const float* W6 = (const float*)d_in[11];
  const float* b6 = (const float*)d_in[12];
  const int* esrc = (const int*)d_in[13];
  const int* edst = (const int*)d_in[14];

  const int nmov = in_sizes[0] / 16;
  const int ne   = in_sizes[13];
  const int nph  = out_size;

  char* ws = (char*)d_ws;
  size_t off = 0;
  auto take = [&](size_t bytes) {
    char* p = ws + off;
    off = (off + bytes + 255) & ~(size_t)255;
    return p;
  };
  unsigned short* hbuf = (unsigned short*)take((size_t)nmov * 128 * 2); // 128 MB
  int* csr             = (int*)take((size_t)ne * 4);                   //   4 MB
  int* cnt             = (int*)take((size_t)nph * 4);
  int* offs            = (int*)take(((size_t)nph + 1) * 4);
  int* cursor          = (int*)take((size_t)nph * 4);
  unsigned short* aggb = (unsigned short*)take((size_t)nph * 128 * 2); //  32 MB
  unsigned short* w1t  = (unsigned short*)take(128 * 32 * 2);
  unsigned short* w2t  = (unsigned short*)take(128 * 128 * 2);
  unsigned short* w3t  = (unsigned short*)take(128 * 128 * 2);
  if (off > ws_size) return;

  hipMemsetAsync(cnt, 0, (size_t)nph * 4, stream);

  prep_weights<<<64, 256, 0, stream>>>(W1, W2, W3, w1t, w2t, w3t);

  int movBlocks = (nmov + 63) / 64;
  mov_mlp_mfma<<<movBlocks, 256, 0, stream>>>(x, w1t, w2t, w3t, b1, b2, b3, hbuf, nmov);

  hist_kernel<<<1024, 256, 0, stream>>>(edst, cnt, ne);
  scan_kernel<<<1, 1024, 0, stream>>>(cnt, offs, cursor, nph);
  fill_kernel<<<1024, 256, 0, stream>>>(esrc, edst, cursor, csr, ne);

  int aggBlocks = (nph + 3) / 4;
  agg_kernel<<<aggBlocks, 256, 0, stream>>>(hbuf, csr, offs, aggb, nph);

  int phBlocks = (nph + 127) / 128;
  phase_mlp_kernel<<<phBlocks, 256, 0, stream>>>(aggb, W4, b4, W5, b5, W6, b6,
                                                 (float*)d_out, nph);
}

// Round 7
// 442.129 us; speedup vs baseline: 5.4085x; 1.8666x over previous
//
#include <hip/hip_runtime.h>
#include <hip/hip_bf16.h>

// ---------------------------------------------------------------------------
// GraphActorNetwork: movement MLP (16->128->128->128) -> scatter-mean over
// edges -> phase MLP (128->128->128->1).
// Round 7: (1) single-block scan (283us, 0.15% occupancy, latency-bound)
// replaced by 3-kernel hierarchical scan (~15us). (2) phase MLP moved to
// bf16 MFMA (same fragment layout as the validated mov_mlp_mfma), head
// computed in-register via 16-lane shfl_xor butterfly. mov MLP + CSR path
// unchanged from round 6 (825us, absmax 3.9e-3).
// ---------------------------------------------------------------------------

typedef __attribute__((ext_vector_type(8))) short short8;
typedef __attribute__((ext_vector_type(4))) float f32x4;

__device__ __forceinline__ float bf2f(unsigned short u) {
  return __uint_as_float(((unsigned int)u) << 16);
}
__device__ __forceinline__ unsigned short f2bf(float f) {
  unsigned int u = __float_as_uint(f);
  u = (u + 0x7fffu + ((u >> 16) & 1u)) >> 16;   // RNE
  return (unsigned short)u;
}

// ---------------- weight prep: f32 -> bf16 transposed -----------------------
// w1t: [128 c][32 k] (k 16..31 zero);  w2t..w5t: [128 c][128 k]
__global__ __launch_bounds__(256)
void prep_weights(const float* __restrict__ W1, const float* __restrict__ W2,
                  const float* __restrict__ W3, const float* __restrict__ W4,
                  const float* __restrict__ W5,
                  unsigned short* __restrict__ w1t, unsigned short* __restrict__ w2t,
                  unsigned short* __restrict__ w3t, unsigned short* __restrict__ w4t,
                  unsigned short* __restrict__ w5t) {
  int t = blockIdx.x * blockDim.x + threadIdx.x;
  int stride = gridDim.x * blockDim.x;
  if (t < 128 * 32) {
    int c = t >> 5, k = t & 31;
    w1t[t] = (k < 16) ? f2bf(W1[k * 128 + c]) : 0;
  }
  for (int i = t; i < 128 * 128; i += stride) {
    int c = i >> 7, k = i & 127;
    w2t[i] = f2bf(W2[k * 128 + c]);
    w3t[i] = f2bf(W3[k * 128 + c]);
    w4t[i] = f2bf(W4[k * 128 + c]);
    w5t[i] = f2bf(W5[k * 128 + c]);
  }
}

// ---------------- movement MLP via MFMA (unchanged from round 6) ------------
// Block: 256 threads = 4 waves, tile 64 rows x 128 cols.
// Wave w: rows (w&1)*32..+31, cols (w>>1)*64..+63 (2 row-frags x 4 col-frags).
// sH: bf16 [64][128], 16B granules XOR-swizzled by (row&7).
__global__ __launch_bounds__(256)
void mov_mlp_mfma(const float* __restrict__ x,
                  const unsigned short* __restrict__ w1t,
                  const unsigned short* __restrict__ w2t,
                  const unsigned short* __restrict__ w3t,
                  const float* __restrict__ b1, const float* __restrict__ b2,
                  const float* __restrict__ b3,
                  unsigned short* __restrict__ hout, int nrows) {
  __shared__ unsigned short sH[64 * 128];
  const int tid  = threadIdx.x;
  const int lane = tid & 63;
  const int w    = tid >> 6;
  const int rloc = lane & 15;
  const int g    = lane >> 4;
  const int r0w  = (w & 1) * 32;
  const int c0   = (w >> 1) * 64;
  const int rowBlk = blockIdx.x * 64;

  f32x4 acc[2][4];
  short8 Bf[4][4];

  // ---- layer 1: A from global x (K=32, cols 16..31 zero) ----
#pragma unroll
  for (int rf = 0; rf < 2; ++rf)
#pragma unroll
    for (int cf = 0; cf < 4; ++cf) acc[rf][cf] = (f32x4)0.f;

  {
    short8 Ax[2];
#pragma unroll
    for (int rf = 0; rf < 2; ++rf) {
      short8 a = (short8)0;
      int row = rowBlk + r0w + rf * 16 + rloc;
      if (g < 2 && row < nrows) {
        const float* xp = x + (size_t)row * 16 + g * 8;
        float4 u0 = *(const float4*)xp;
        float4 u1 = *(const float4*)(xp + 4);
        a[0] = (short)f2bf(u0.x); a[1] = (short)f2bf(u0.y);
        a[2] = (short)f2bf(u0.z); a[3] = (short)f2bf(u0.w);
        a[4] = (short)f2bf(u1.x); a[5] = (short)f2bf(u1.y);
        a[6] = (short)f2bf(u1.z); a[7] = (short)f2bf(u1.w);
      }
      Ax[rf] = a;
    }
    short8 B1[4];
#pragma unroll
    for (int cf = 0; cf < 4; ++cf)
      B1[cf] = *(const short8*)&w1t[(c0 + cf * 16 + rloc) * 32 + g * 8];
#pragma unroll
    for (int rf = 0; rf < 2; ++rf)
#pragma unroll
      for (int cf = 0; cf < 4; ++cf)
        acc[rf][cf] = __builtin_amdgcn_mfma_f32_16x16x32_bf16(Ax[rf], B1[cf], acc[rf][cf], 0, 0, 0);
  }

  {
    float bv[4];
#pragma unroll
    for (int cf = 0; cf < 4; ++cf) bv[cf] = b1[c0 + cf * 16 + rloc];
#pragma unroll
    for (int rf = 0; rf < 2; ++rf)
#pragma unroll
      for (int cf = 0; cf < 4; ++cf)
#pragma unroll
        for (int i = 0; i < 4; ++i) {
          int row = r0w + rf * 16 + g * 4 + i;
          int col = c0 + cf * 16 + rloc;
          float v = fmaxf(acc[rf][cf][i] + bv[cf], 0.f);
          sH[row * 128 + (((col >> 3) ^ (row & 7)) << 3) + (col & 7)] = f2bf(v);
        }
  }
  __syncthreads();

  const unsigned short* wts[2] = { w2t, w3t };
  const float* bs[2] = { b2, b3 };
#pragma unroll 1
  for (int layer = 0; layer < 2; ++layer) {
    const unsigned short* wt = wts[layer];
#pragma unroll
    for (int ks = 0; ks < 4; ++ks)
#pragma unroll
      for (int cf = 0; cf < 4; ++cf)
        Bf[ks][cf] = *(const short8*)&wt[(c0 + cf * 16 + rloc) * 128 + ks * 32 + g * 8];

#pragma unroll
    for (int rf = 0; rf < 2; ++rf)
#pragma unroll
      for (int cf = 0; cf < 4; ++cf) acc[rf][cf] = (f32x4)0.f;

#pragma unroll
    for (int ks = 0; ks < 4; ++ks) {
      short8 A0, A1;
      {
        int row = r0w + rloc;
        int slot = (ks * 4 + g) ^ (row & 7);
        A0 = *(const short8*)&sH[row * 128 + slot * 8];
      }
      {
        int row = r0w + 16 + rloc;
        int slot = (ks * 4 + g) ^ (row & 7);
        A1 = *(const short8*)&sH[row * 128 + slot * 8];
      }
#pragma unroll
      for (int cf = 0; cf < 4; ++cf) {
        acc[0][cf] = __builtin_amdgcn_mfma_f32_16x16x32_bf16(A0, Bf[ks][cf], acc[0][cf], 0, 0, 0);
        acc[1][cf] = __builtin_amdgcn_mfma_f32_16x16x32_bf16(A1, Bf[ks][cf], acc[1][cf], 0, 0, 0);
      }
    }
    __syncthreads();

    const float* bb = bs[layer];
    float bv[4];
#pragma unroll
    for (int cf = 0; cf < 4; ++cf) bv[cf] = bb[c0 + cf * 16 + rloc];
#pragma unroll
    for (int rf = 0; rf < 2; ++rf)
#pragma unroll
      for (int cf = 0; cf < 4; ++cf)
#pragma unroll
        for (int i = 0; i < 4; ++i) {
          int row = r0w + rf * 16 + g * 4 + i;
          int col = c0 + cf * 16 + rloc;
          float v = fmaxf(acc[rf][cf][i] + bv[cf], 0.f);
          sH[row * 128 + (((col >> 3) ^ (row & 7)) << 3) + (col & 7)] = f2bf(v);
        }
    __syncthreads();
  }

  {
    int row = tid >> 2;
    int q   = tid & 3;
    int grow = rowBlk + row;
    if (grow < nrows) {
#pragma unroll
      for (int i = 0; i < 4; ++i) {
        int gidx = q * 4 + i;
        int slot = gidx ^ (row & 7);
        short8 v = *(const short8*)&sH[row * 128 + slot * 8];
        *(short8*)(hout + (size_t)grow * 128 + gidx * 8) = v;
      }
    }
  }
}

// ---------------- CSR build ------------------------------------------------
__global__ __launch_bounds__(256)
void hist_kernel(const int* __restrict__ edst, int* __restrict__ cnt, int ne) {
  int i = blockIdx.x * blockDim.x + threadIdx.x;
  int stride = gridDim.x * blockDim.x;
  for (int e = i; e < ne; e += stride) atomicAdd(cnt + edst[e], 1);
}

// hierarchical scan: 1024 elems per block. s1: per-block sums.
__global__ __launch_bounds__(256)
void scan_sum_kernel(const int* __restrict__ cnt, int* __restrict__ bsum, int nph) {
  __shared__ int red[256];
  const int b = blockIdx.x, t = threadIdx.x;
  const int base = b * 1024 + t * 4;
  int s = 0;
#pragma unroll
  for (int i = 0; i < 4; ++i) {
    int idx = base + i;
    if (idx < nph) s += cnt[idx];
  }
  red[t] = s;
  __syncthreads();
  for (int d = 128; d > 0; d >>= 1) {
    if (t < d) red[t] += red[t + d];
    __syncthreads();
  }
  if (t == 0) bsum[b] = red[0];
}

// s2: exclusive scan of bsum[nb] (nb <= 256) -> boff; total -> *offs_end.
__global__ __launch_bounds__(256)
void scan_top_kernel(const int* __restrict__ bsum, int* __restrict__ boff,
                     int* __restrict__ offs_end, int nb) {
  __shared__ int part[256];
  const int t = threadIdx.x;
  part[t] = (t < nb) ? bsum[t] : 0;
  __syncthreads();
  for (int d = 1; d < 256; d <<= 1) {
    int v = (t >= d) ? part[t - d] : 0;
    __syncthreads();
    part[t] += v;
    __syncthreads();
  }
  if (t < nb) boff[t] = (t == 0) ? 0 : part[t - 1];
  if (t == 255) *offs_end = part[255];
}

// s3: per-block exclusive scan + base offset -> offs, cursor.
__global__ __launch_bounds__(256)
void scan_fill_kernel(const int* __restrict__ cnt, const int* __restrict__ boff,
                      int* __restrict__ offs, int* __restrict__ cursor, int nph) {
  __shared__ int part[256];
  const int b = blockIdx.x, t = threadIdx.x;
  const int base = b * 1024 + t * 4;
  int v[4];
  int s = 0;
#pragma unroll
  for (int i = 0; i < 4; ++i) {
    int idx = base + i;
    v[i] = (idx < nph) ? cnt[idx] : 0;
    s += v[i];
  }
  part[t] = s;
  __syncthreads();
  for (int d = 1; d < 256; d <<= 1) {
    int u = (t >= d) ? part[t - d] : 0;
    __syncthreads();
    part[t] += u;
    __syncthreads();
  }
  int run = boff[b] + ((t == 0) ? 0 : part[t - 1]);
#pragma unroll
  for (int i = 0; i < 4; ++i) {
    int idx = base + i;
    if (idx < nph) {
      offs[idx] = run;
      cursor[idx] = run;
      run += v[i];
    }
  }
}

__global__ __launch_bounds__(256)
void fill_kernel(const int* __restrict__ esrc, const int* __restrict__ edst,
                 int* __restrict__ cursor, int* __restrict__ csr, int ne) {
  int i = blockIdx.x * blockDim.x + threadIdx.x;
  int stride = gridDim.x * blockDim.x;
  for (int e = i; e < ne; e += stride) {
    int d = edst[e];
    int pos = atomicAdd(cursor + d, 1);
    csr[pos] = esrc[e];
  }
}

// ---------------- per-phase gather-reduce: one wave per phase ---------------
__global__ __launch_bounds__(256)
void agg_kernel(const unsigned short* __restrict__ h, const int* __restrict__ csr,
                const int* __restrict__ offs, unsigned short* __restrict__ agg,
                int nph) {
  const int w = (blockIdx.x * blockDim.x + threadIdx.x) >> 6;
  const int lane = threadIdx.x & 63;
  if (w >= nph) return;
  const int beg = offs[w], end = offs[w + 1];
  float a0 = 0.f, a1 = 0.f;
  for (int j = beg; j < end; ++j) {
    int s = csr[j];
    ushort2 v = *(const ushort2*)(h + (size_t)s * 128 + lane * 2);
    a0 += bf2f(v.x);
    a1 += bf2f(v.y);
  }
  const float sc = 1.f / (float)max(end - beg, 1);
  ushort2 o;
  o.x = f2bf(a0 * sc);
  o.y = f2bf(a1 * sc);
  *(ushort2*)(agg + (size_t)w * 128 + lane * 2) = o;
}

// ---------------- phase MLP via MFMA ----------------------------------------
// Same tile/wave decomposition as mov_mlp_mfma. Layer 4 A-frags straight from
// aggb (bf16 row-major: short8 at [row][ks*32+g*8] matches A layout). Layer 5
// output never leaves registers: head = relu(acc+b5) . W6 reduced across the
// 16 rloc lanes via shfl_xor, col-halves combined through LDS.
__global__ __launch_bounds__(256)
void phase_mlp_mfma(const unsigned short* __restrict__ aggb,
                    const unsigned short* __restrict__ w4t,
                    const unsigned short* __restrict__ w5t,
                    const float* __restrict__ b4, const float* __restrict__ b5,
                    const float* __restrict__ W6, const float* __restrict__ b6,
                    float* __restrict__ logits, int nph) {
  __shared__ unsigned short sH[64 * 128];
  float* sPart = (float*)sH;   // reused (after barrier) for head partials
  const int tid  = threadIdx.x;
  const int lane = tid & 63;
  const int w    = tid >> 6;
  const int rloc = lane & 15;
  const int g    = lane >> 4;
  const int r0w  = (w & 1) * 32;
  const int c0   = (w >> 1) * 64;
  const int rowBlk = blockIdx.x * 64;

  f32x4 acc[2][4];
  short8 Bf[4][4];

  // ---- layer 4: A from aggb global ----
#pragma unroll
  for (int ks = 0; ks < 4; ++ks)
#pragma unroll
    for (int cf = 0; cf < 4; ++cf)
      Bf[ks][cf] = *(const short8*)&w4t[(c0 + cf * 16 + rloc) * 128 + ks * 32 + g * 8];
#pragma unroll
  for (int rf = 0; rf < 2; ++rf)
#pragma unroll
    for (int cf = 0; cf < 4; ++cf) acc[rf][cf] = (f32x4)0.f;

  {
    const int row0 = rowBlk + r0w + rloc;
    const int row1 = row0 + 16;
#pragma unroll
    for (int ks = 0; ks < 4; ++ks) {
      short8 A0 = (short8)0, A1 = (short8)0;
      if (row0 < nph) A0 = *(const short8*)&aggb[(size_t)row0 * 128 + ks * 32 + g * 8];
      if (row1 < nph) A1 = *(const short8*)&aggb[(size_t)row1 * 128 + ks * 32 + g * 8];
#pragma unroll
      for (int cf = 0; cf < 4; ++cf) {
        acc[0][cf] = __builtin_amdgcn_mfma_f32_16x16x32_bf16(A0, Bf[ks][cf], acc[0][cf], 0, 0, 0);
        acc[1][cf] = __builtin_amdgcn_mfma_f32_16x16x32_bf16(A1, Bf[ks][cf], acc[1][cf], 0, 0, 0);
      }
    }
  }

  // epilogue layer 4 -> sH (swizzled, same as mov)
  {
    float bv[4];
#pragma unroll
    for (int cf = 0; cf < 4; ++cf) bv[cf] = b4[c0 + cf * 16 + rloc];
#pragma unroll
    for (int rf = 0; rf < 2; ++rf)
#pragma unroll
      for (int cf = 0; cf < 4; ++cf)
#pragma unroll
        for (int i = 0; i < 4; ++i) {
          int row = r0w + rf * 16 + g * 4 + i;
          int col = c0 + cf * 16 + rloc;
          float v = fmaxf(acc[rf][cf][i] + bv[cf], 0.f);
          sH[row * 128 + (((col >> 3) ^ (row & 7)) << 3) + (col & 7)] = f2bf(v);
        }
  }
  __syncthreads();

  // ---- layer 5: A from sH ----
#pragma unroll
  for (int ks = 0; ks < 4; ++ks)
#pragma unroll
    for (int cf = 0; cf < 4; ++cf)
      Bf[ks][cf] = *(const short8*)&w5t[(c0 + cf * 16 + rloc) * 128 + ks * 32 + g * 8];
#pragma unroll
  for (int rf = 0; rf < 2; ++rf)
#pragma unroll
    for (int cf = 0; cf < 4; ++cf) acc[rf][cf] = (f32x4)0.f;

#pragma unroll
  for (int ks = 0; ks < 4; ++ks) {
    short8 A0, A1;
    {
      int row = r0w + rloc;
      int slot = (ks * 4 + g) ^ (row & 7);
      A0 = *(const short8*)&sH[row * 128 + slot * 8];
    }
    {
      int row = r0w + 16 + rloc;
      int slot = (ks * 4 + g) ^ (row & 7);
      A1 = *(const short8*)&sH[row * 128 + slot * 8];
    }
#pragma unroll
    for (int cf = 0; cf < 4; ++cf) {
      acc[0][cf] = __builtin_amdgcn_mfma_f32_16x16x32_bf16(A0, Bf[ks][cf], acc[0][cf], 0, 0, 0);
      acc[1][cf] = __builtin_amdgcn_mfma_f32_16x16x32_bf16(A1, Bf[ks][cf], acc[1][cf], 0, 0, 0);
    }
  }

  // ---- head: logits[r] = relu(acc + b5) . W6 + b6 ----
  float part8[2][4];
  {
    float bv[4], wv[4];
#pragma unroll
    for (int cf = 0; cf < 4; ++cf) {
      bv[cf] = b5[c0 + cf * 16 + rloc];
      wv[cf] = W6[c0 + cf * 16 + rloc];
    }
#pragma unroll
    for (int rf = 0; rf < 2; ++rf)
#pragma unroll
      for (int i = 0; i < 4; ++i) {
        float p = 0.f;
#pragma unroll
        for (int cf = 0; cf < 4; ++cf)
          p += fmaxf(acc[rf][cf][i] + bv[cf], 0.f) * wv[cf];
        part8[rf][i] = p;
      }
  }
  // butterfly over the 16 rloc lanes (same g group)
#pragma unroll
  for (int m = 1; m < 16; m <<= 1) {
#pragma unroll
    for (int rf = 0; rf < 2; ++rf)
#pragma unroll
      for (int i = 0; i < 4; ++i)
        part8[rf][i] += __shfl_xor(part8[rf][i], m, 64);
  }
  __syncthreads();   // all sH (bf16) reads done before float reuse
  if (rloc == 0) {
#pragma unroll
    for (int rf = 0; rf < 2; ++rf)
#pragma unroll
      for (int i = 0; i < 4; ++i)
        sPart[(w >> 1) * 64 + r0w + rf * 16 + g * 4 + i] = part8[rf][i];
  }
  __syncthreads();
  if (tid < 64) {
    int gr = rowBlk + tid;
    if (gr < nph) logits[gr] = sPart[tid] + sPart[64 + tid] + b6[0];
  }
}

// ---------------------------------------------------------------------------
extern "C" void kernel_launch(void* const* d_in, const int* in_sizes, int n_in,
                              void* d_out, int out_size, void* d_ws, size_t ws_size,
                              hipStream_t stream) {
  const float* x  = (const float*)d_in[0];
  const float* W1 = (const float*)d_in[1];
  const float* b1 = (const float*)d_in[2];
  const float* W2 = (const float*)d_in[3];
  const float* b2 = (const float*)d_in[4];
  const float* W3 = (const float*)d_in[5];
  const float* b3 = (const float*)d_in[6];
  const float* W4 = (const float*)d_in[7];
  const float* b4 = (const float*)d_in[8];
  const float* W5 = (const float*)d_in[9];
  const float* b5 = (const float*)d_in[10];
  const float* W6 = (const float*)d_in[11];
  const float* b6 = (const float*)d_in[12];
  const int* esrc = (const int*)d_in[13];
  const int* edst = (const int*)d_in[14];

  const int nmov = in_sizes[0] / 16;
  const int ne   = in_sizes[13];
  const int nph  = out_size;

  char* ws = (char*)d_ws;
  size_t off = 0;
  auto take = [&](size_t bytes) {
    char* p = ws + off;
    off = (off + bytes + 255) & ~(size_t)255;
    return p;
  };
  unsigned short* hbuf = (unsigned short*)take((size_t)nmov * 128 * 2); // 128 MB
  int* csr             = (int*)take((size_t)ne * 4);                   //   4 MB
  int* cnt             = (int*)take((size_t)nph * 4);
  int* offs            = (int*)take(((size_t)nph + 1) * 4);
  int* cursor          = (int*)take((size_t)nph * 4);
  unsigned short* aggb = (unsigned short*)take((size_t)nph * 128 * 2); //  32 MB
  unsigned short* w1t  = (unsigned short*)take(128 * 32 * 2);
  unsigned short* w2t  = (unsigned short*)take(128 * 128 * 2);
  unsigned short* w3t  = (unsigned short*)take(128 * 128 * 2);
  unsigned short* w4t  = (unsigned short*)take(128 * 128 * 2);
  unsigned short* w5t  = (unsigned short*)take(128 * 128 * 2);
  const int nb = (nph + 1023) / 1024;            // <= 256 for nph <= 262144
  int* bsum            = (int*)take((size_t)nb * 4);
  int* boff            = (int*)take((size_t)nb * 4);
  if (off > ws_size) return;

  hipMemsetAsync(cnt, 0, (size_t)nph * 4, stream);

  prep_weights<<<64, 256, 0, stream>>>(W1, W2, W3, W4, W5, w1t, w2t, w3t, w4t, w5t);

  int movBlocks = (nmov + 63) / 64;
  mov_mlp_mfma<<<movBlocks, 256, 0, stream>>>(x, w1t, w2t, w3t, b1, b2, b3, hbuf, nmov);

  hist_kernel<<<1024, 256, 0, stream>>>(edst, cnt, ne);
  scan_sum_kernel<<<nb, 256, 0, stream>>>(cnt, bsum, nph);
  scan_top_kernel<<<1, 256, 0, stream>>>(bsum, boff, offs + nph, nb);
  scan_fill_kernel<<<nb, 256, 0, stream>>>(cnt, boff, offs, cursor, nph);
  fill_kernel<<<1024, 256, 0, stream>>>(esrc, edst, cursor, csr, ne);

  int aggBlocks = (nph + 3) / 4;
  agg_kernel<<<aggBlocks, 256, 0, stream>>>(hbuf, csr, offs, aggb, nph);

  int phBlocks = (nph + 63) / 64;
  phase_mlp_mfma<<<phBlocks, 256, 0, stream>>>(aggb, w4t, w5t, b4, b5, W6, b6,
                                               (float*)d_out, nph);
}